// Round 6
// baseline (411.145 us; speedup 1.0000x reference)
//
#include <hip/hip_runtime.h>
#include <math.h>

static inline size_t align256(size_t x) { return (x + 255) & ~(size_t)255; }

typedef __attribute__((ext_vector_type(8))) short bf16x8;
typedef __attribute__((ext_vector_type(4))) float f32x4;

// ---- bf16 helpers (fp32 accumulate everywhere; bf16 is storage only) ----
__device__ inline float bfLo(unsigned int u) {
  union { unsigned int i; float f; } v; v.i = u << 16; return v.f;
}
__device__ inline float bfHi(unsigned int u) {
  union { unsigned int i; float f; } v; v.i = u & 0xffff0000u; return v.f;
}
__device__ inline float bf2f(unsigned short u) {
  union { unsigned int i; float f; } v; v.i = ((unsigned int)u) << 16; return v.f;
}
__device__ inline unsigned short f2bf(float f) {
  union { float f; unsigned int i; } v; v.f = f;
  unsigned int r = v.i + 0x7FFF + ((v.i >> 16) & 1);  // RNE
  return (unsigned short)(r >> 16);
}
__device__ inline unsigned int packbf(float lo, float hi) {
  return ((unsigned int)f2bf(hi) << 16) | f2bf(lo);
}

// ============ graph build: two-level LDS-privatized binning ============
__global__ __launch_bounds__(256) void k_coarse_count(const int* __restrict__ esrc,
                                                      const int* __restrict__ edst,
                                                      int E, int chunk, int NB, int G,
                                                      int* __restrict__ blkD,
                                                      int* __restrict__ blkS) {
  __shared__ int hD[512], hS[512];
  int blk = blockIdx.x, tid = threadIdx.x;
  for (int i = tid; i < NB; i += 256) { hD[i] = 0; hS[i] = 0; }
  __syncthreads();
  int s0 = blk * chunk, s1 = min(E, s0 + chunk);
  for (int e = s0 + tid; e < s1; e += 256) {
    atomicAdd(&hD[edst[e] >> 8], 1);
    atomicAdd(&hS[esrc[e] >> 8], 1);
  }
  __syncthreads();
  for (int i = tid; i < NB; i += 256) {
    blkD[i * G + blk] = hD[i];
    blkS[i * G + blk] = hS[i];
  }
}

__global__ __launch_bounds__(256) void k_scan1(const int* __restrict__ in,
                                               int* __restrict__ out,
                                               int* __restrict__ bsums, int n) {
  __shared__ int s[256];
  int tid = threadIdx.x, gid = blockIdx.x * 256 + tid;
  int v = (gid < n) ? in[gid] : 0;
  s[tid] = v; __syncthreads();
  for (int o = 1; o < 256; o <<= 1) {
    int t = (tid >= o) ? s[tid - o] : 0;
    __syncthreads();
    s[tid] += t;
    __syncthreads();
  }
  if (gid < n) out[gid] = s[tid] - v;
  if (tid == 255) bsums[blockIdx.x] = s[255];
}

__global__ __launch_bounds__(512) void k_scan2(int* __restrict__ bsums, int nb) {
  __shared__ int s[512];
  int tid = threadIdx.x;
  int v = (tid < nb) ? bsums[tid] : 0;
  s[tid] = v; __syncthreads();
  for (int o = 1; o < 512; o <<= 1) {
    int t = (tid >= o) ? s[tid - o] : 0;
    __syncthreads();
    s[tid] += t;
    __syncthreads();
  }
  if (tid < nb) bsums[tid] = s[tid] - v;
}

__global__ __launch_bounds__(256) void k_scan3b(int* __restrict__ arr,
                                                const int* __restrict__ bsums, int n) {
  int gid = blockIdx.x * 256 + threadIdx.x;
  if (gid < n) arr[gid] += bsums[blockIdx.x];
}

// P3: packed scatter. pair = (src<<8)|(dst&255): src<2^17 fits, dst fine index 8b.
__global__ __launch_bounds__(256) void k_coarse_scatter(const int* __restrict__ esrc,
                                                        const int* __restrict__ edst,
                                                        int E, int chunk, int NB, int G,
                                                        const int* __restrict__ scD,
                                                        const int* __restrict__ scS,
                                                        unsigned int* __restrict__ pairs,
                                                        unsigned int* __restrict__ keys) {
  __shared__ int cD[512], cS[512];
  int blk = blockIdx.x, tid = threadIdx.x;
  for (int i = tid; i < NB; i += 256) {
    cD[i] = scD[i * G + blk];
    cS[i] = scS[i * G + blk];
  }
  __syncthreads();
  int s0 = blk * chunk, s1 = min(E, s0 + chunk);
  for (int e = s0 + tid; e < s1; e += 256) {
    int s = esrc[e], d = edst[e];
    int pd = atomicAdd(&cD[d >> 8], 1);
    pairs[pd] = ((unsigned)s << 8) | ((unsigned)d & 255u);
    int ps = atomicAdd(&cS[s >> 8], 1);
    keys[ps] = (unsigned)s;
  }
}

__global__ __launch_bounds__(256) void k_fine_dst(const unsigned int* __restrict__ pairs,
                                                  const int* __restrict__ scD,
                                                  int G, int E, int N, int NB,
                                                  int* __restrict__ cntIn,
                                                  float* __restrict__ normIn,
                                                  int* __restrict__ offs,
                                                  int* __restrict__ csr) {
  __shared__ int hist[256], scn[256], cur[256];
  int b = blockIdx.x, tid = threadIdx.x;
  int bstart = scD[b * G];
  int bend = (b + 1 < NB) ? scD[(b + 1) * G] : E;
  hist[tid] = 0;
  __syncthreads();
  for (int e = bstart + tid; e < bend; e += 256)
    atomicAdd(&hist[pairs[e] & 255u], 1);
  __syncthreads();
  int v = hist[tid];
  scn[tid] = v;
  __syncthreads();
  for (int o = 1; o < 256; o <<= 1) {
    int t = (tid >= o) ? scn[tid - o] : 0;
    __syncthreads();
    scn[tid] += t;
    __syncthreads();
  }
  int excl = scn[tid] - v;
  cur[tid] = excl;
  int node = b * 256 + tid;
  if (node < N) {
    cntIn[node] = v;
    normIn[node] = rsqrtf((float)max(v, 1));
    offs[node] = bstart + excl;
  }
  __syncthreads();
  for (int e = bstart + tid; e < bend; e += 256) {
    unsigned int u = pairs[e];
    int p = bstart + atomicAdd(&cur[u & 255u], 1);
    csr[p] = (int)(u >> 8);
  }
}

__global__ __launch_bounds__(256) void k_fine_src(const unsigned int* __restrict__ keys,
                                                  const int* __restrict__ scS,
                                                  int G, int E, int N, int NB,
                                                  float* __restrict__ normOut) {
  __shared__ int hist[256];
  int b = blockIdx.x, tid = threadIdx.x;
  int bstart = scS[b * G];
  int bend = (b + 1 < NB) ? scS[(b + 1) * G] : E;
  hist[tid] = 0;
  __syncthreads();
  for (int e = bstart + tid; e < bend; e += 256)
    atomicAdd(&hist[keys[e] & 255u], 1);
  __syncthreads();
  int node = b * 256 + tid;
  if (node < N) normOut[node] = rsqrtf((float)max(hist[tid], 1));
}

// ---------------- weight prep: W[K x C] fp32 -> Wt[C x K] bf16 (n-major) ----------------
__global__ __launch_bounds__(256) void k_prep(const float* __restrict__ W1,
                                              const float* __restrict__ W2,
                                              unsigned short* __restrict__ W1t,
                                              unsigned short* __restrict__ W2t) {
  int t = blockIdx.x * 256 + threadIdx.x;
  int stride = gridDim.x * 256;
  for (int i = t; i < 128 * 128; i += stride) {
    int nn = i >> 7, kk = i & 127;
    W1t[i] = f2bf(W1[kk * 128 + nn]);
  }
  for (int i = t; i < 64 * 128; i += stride) {
    int nn = i >> 7, kk = i & 127;
    W2t[i] = f2bf(W2[kk * 64 + nn]);
  }
}

// ---------------- MFMA GEMM (layer 1): X1 = diag(normOut)*feat @ W1 ----------------
template <int C, typename TA>
__global__ __launch_bounds__(256) void k_mgemm(const TA* __restrict__ A,
                                               const float* __restrict__ scale,
                                               const unsigned short* __restrict__ Wt,
                                               unsigned short* __restrict__ out, int n) {
  constexpr int KP = 136;
  constexpr int NCH = C / 16;
  __shared__ __align__(16) unsigned short Al[64 * KP];
  __shared__ __align__(16) unsigned short Wl[C * KP];
  int tid = threadIdx.x;
  int r0 = blockIdx.x * 64;

  {
    const uint4* Wg = (const uint4*)Wt;
    uint4* Wd = (uint4*)Wl;
    for (int idx = tid; idx < C * 16; idx += 256) {
      int row = idx >> 4, seg = idx & 15;
      Wd[row * 17 + seg] = Wg[idx];
    }
  }
  {
    int seg = tid & 7;
    for (int it = 0; it < 2; ++it) {
      int row = (tid >> 3) + it * 32;
      int g = r0 + row;
      float v[16];
      if (g < n) {
        float sc = scale[g];
        if constexpr (sizeof(TA) == 4) {
          const float4* Ag = (const float4*)((const float*)A + (size_t)g * 128);
#pragma unroll
          for (int j = 0; j < 4; ++j) {
            float4 f = Ag[seg * 4 + j];
            v[j * 4 + 0] = f.x * sc; v[j * 4 + 1] = f.y * sc;
            v[j * 4 + 2] = f.z * sc; v[j * 4 + 3] = f.w * sc;
          }
        } else {
          const uint4* Ag = (const uint4*)((const unsigned short*)A + (size_t)g * 128);
#pragma unroll
          for (int j = 0; j < 2; ++j) {
            uint4 u = Ag[seg * 2 + j];
            v[j * 8 + 0] = bfLo(u.x) * sc; v[j * 8 + 1] = bfHi(u.x) * sc;
            v[j * 8 + 2] = bfLo(u.y) * sc; v[j * 8 + 3] = bfHi(u.y) * sc;
            v[j * 8 + 4] = bfLo(u.z) * sc; v[j * 8 + 5] = bfHi(u.z) * sc;
            v[j * 8 + 6] = bfLo(u.w) * sc; v[j * 8 + 7] = bfHi(u.w) * sc;
          }
        }
      } else {
#pragma unroll
        for (int j = 0; j < 16; ++j) v[j] = 0.f;
      }
      uint4* dst = (uint4*)(Al + row * KP + seg * 16);
      dst[0] = make_uint4(packbf(v[0], v[1]), packbf(v[2], v[3]),
                          packbf(v[4], v[5]), packbf(v[6], v[7]));
      dst[1] = make_uint4(packbf(v[8], v[9]), packbf(v[10], v[11]),
                          packbf(v[12], v[13]), packbf(v[14], v[15]));
    }
  }
  __syncthreads();

  int lane = tid & 63;
  int w = tid >> 6;
  int quad = lane >> 4, m16 = lane & 15;
  f32x4 acc[NCH];
#pragma unroll
  for (int c = 0; c < NCH; ++c) acc[c] = (f32x4){0.f, 0.f, 0.f, 0.f};

#pragma unroll
  for (int kc = 0; kc < 4; ++kc) {
    int ko = kc * 32 + quad * 8;
    bf16x8 a = *(const bf16x8*)(Al + (w * 16 + m16) * KP + ko);
#pragma unroll
    for (int c = 0; c < NCH; ++c) {
      bf16x8 b = *(const bf16x8*)(Wl + (c * 16 + m16) * KP + ko);
      acc[c] = __builtin_amdgcn_mfma_f32_16x16x32_bf16(a, b, acc[c], 0, 0, 0);
    }
  }

#pragma unroll
  for (int c = 0; c < NCH; ++c)
#pragma unroll
    for (int r = 0; r < 4; ++r) {
      int g = r0 + w * 16 + quad * 4 + r;
      if (g < n) out[(size_t)g * C + c * 16 + m16] = f2bf(acc[c][r]);
    }
}

// ---------------- fused layer-1 agg + layer-2 GEMM ----------------
// Block = 64 dst nodes (wave w owns nodes w*16..w*16+15, gathered serially —
// per-wave work = sum of 16 Poisson(16) degrees, sigma/mu ~6%).
// Per node: h1 = relu(agg(X1)*normIn + b1); LDS A-row = h1*normOut (bf16).
// Then the proven mgemm<64> MFMA phase: X2 = Atile @ W2t. H1 never hits global.
__global__ __launch_bounds__(256) void k_agg1_fused(const unsigned short* __restrict__ X,
                                                    const int* __restrict__ csr,
                                                    const int* __restrict__ offs,
                                                    const int* __restrict__ cnt,
                                                    const float* __restrict__ normIn,
                                                    const float* __restrict__ normOut,
                                                    const float* __restrict__ bias,
                                                    const unsigned short* __restrict__ W2t,
                                                    unsigned short* __restrict__ X2, int n) {
  constexpr int KP = 136;
  __shared__ __align__(16) unsigned short Al[64 * KP];
  __shared__ __align__(16) unsigned short Wl[64 * KP];
  int tid = threadIdx.x;
  int lane = tid & 63;
  int w = tid >> 6;
  int r0 = blockIdx.x * 64;

  // stage W2t (64 x 128 bf16, n-major) -> LDS
  {
    const uint4* Wg = (const uint4*)W2t;
    uint4* Wd = (uint4*)Wl;
    for (int idx = tid; idx < 64 * 16; idx += 256) {
      int row = idx >> 4, seg = idx & 15;
      Wd[row * 17 + seg] = Wg[idx];
    }
  }

  // gather phase: wave w handles nodes r0 + w*16 + nd
  const unsigned int* Xu = (const unsigned int*)X;  // row stride 64 uints
  float bx = bias[lane * 2], by = bias[lane * 2 + 1];
  for (int nd = 0; nd < 16; ++nd) {
    int wid = r0 + w * 16 + nd;
    float hx = 0.f, hy = 0.f;
    if (wid < n) {
      int start = offs[wid], m = cnt[wid];
      const int* p = csr + start;
      float ax = 0.f, ay = 0.f;
      int e = 0;
      for (; e + 8 <= m; e += 8) {
        int s0 = p[e], s1 = p[e + 1], s2 = p[e + 2], s3 = p[e + 3];
        int s4 = p[e + 4], s5 = p[e + 5], s6 = p[e + 6], s7 = p[e + 7];
        unsigned int u0 = Xu[(size_t)s0 * 64 + lane];
        unsigned int u1 = Xu[(size_t)s1 * 64 + lane];
        unsigned int u2 = Xu[(size_t)s2 * 64 + lane];
        unsigned int u3 = Xu[(size_t)s3 * 64 + lane];
        unsigned int u4 = Xu[(size_t)s4 * 64 + lane];
        unsigned int u5 = Xu[(size_t)s5 * 64 + lane];
        unsigned int u6 = Xu[(size_t)s6 * 64 + lane];
        unsigned int u7 = Xu[(size_t)s7 * 64 + lane];
        ax += bfLo(u0); ay += bfHi(u0);
        ax += bfLo(u1); ay += bfHi(u1);
        ax += bfLo(u2); ay += bfHi(u2);
        ax += bfLo(u3); ay += bfHi(u3);
        ax += bfLo(u4); ay += bfHi(u4);
        ax += bfLo(u5); ay += bfHi(u5);
        ax += bfLo(u6); ay += bfHi(u6);
        ax += bfLo(u7); ay += bfHi(u7);
      }
      for (; e + 4 <= m; e += 4) {
        int s0 = p[e], s1 = p[e + 1], s2 = p[e + 2], s3 = p[e + 3];
        unsigned int u0 = Xu[(size_t)s0 * 64 + lane];
        unsigned int u1 = Xu[(size_t)s1 * 64 + lane];
        unsigned int u2 = Xu[(size_t)s2 * 64 + lane];
        unsigned int u3 = Xu[(size_t)s3 * 64 + lane];
        ax += bfLo(u0); ay += bfHi(u0);
        ax += bfLo(u1); ay += bfHi(u1);
        ax += bfLo(u2); ay += bfHi(u2);
        ax += bfLo(u3); ay += bfHi(u3);
      }
      for (; e < m; ++e) {
        unsigned int u = Xu[(size_t)p[e] * 64 + lane];
        ax += bfLo(u); ay += bfHi(u);
      }
      float nmI = normIn[wid], nmO = normOut[wid];
      hx = fmaxf(ax * nmI + bx, 0.f) * nmO;
      hy = fmaxf(ay * nmI + by, 0.f) * nmO;
    }
    *(unsigned int*)(Al + (w * 16 + nd) * KP + lane * 2) = packbf(hx, hy);
  }
  __syncthreads();

  // MFMA phase: X2(64 x 64) = Atile(64 x 128) @ W2t^T
  int quad = lane >> 4, m16 = lane & 15;
  f32x4 acc[4];
#pragma unroll
  for (int c = 0; c < 4; ++c) acc[c] = (f32x4){0.f, 0.f, 0.f, 0.f};
#pragma unroll
  for (int kc = 0; kc < 4; ++kc) {
    int ko = kc * 32 + quad * 8;
    bf16x8 a = *(const bf16x8*)(Al + (w * 16 + m16) * KP + ko);
#pragma unroll
    for (int c = 0; c < 4; ++c) {
      bf16x8 b = *(const bf16x8*)(Wl + (c * 16 + m16) * KP + ko);
      acc[c] = __builtin_amdgcn_mfma_f32_16x16x32_bf16(a, b, acc[c], 0, 0, 0);
    }
  }
#pragma unroll
  for (int c = 0; c < 4; ++c)
#pragma unroll
    for (int r = 0; r < 4; ++r) {
      int g = r0 + w * 16 + quad * 4 + r;
      if (g < n) X2[(size_t)g * 64 + c * 16 + m16] = f2bf(acc[c][r]);
    }
}

// ---------------- layer-2 aggregation (bf16 in/out, fp32 accumulate) ----------------
__global__ __launch_bounds__(256) void k_agg64(const unsigned short* __restrict__ X,
                                               const int* __restrict__ csr,
                                               const int* __restrict__ offs,
                                               const int* __restrict__ cnt,
                                               const float* __restrict__ norm,
                                               const float* __restrict__ bias,
                                               unsigned short* __restrict__ H, int n) {
  int wid = blockIdx.x * 4 + (threadIdx.x >> 6);
  if (wid >= n) return;
  int lane = threadIdx.x & 63;
  int start = offs[wid], m = cnt[wid];
  const int* p = csr + start;
  float a = 0.f;
  int e = 0;
  for (; e + 8 <= m; e += 8) {
    int s0 = p[e], s1 = p[e + 1], s2 = p[e + 2], s3 = p[e + 3];
    int s4 = p[e + 4], s5 = p[e + 5], s6 = p[e + 6], s7 = p[e + 7];
    unsigned short u0 = X[(size_t)s0 * 64 + lane];
    unsigned short u1 = X[(size_t)s1 * 64 + lane];
    unsigned short u2 = X[(size_t)s2 * 64 + lane];
    unsigned short u3 = X[(size_t)s3 * 64 + lane];
    unsigned short u4 = X[(size_t)s4 * 64 + lane];
    unsigned short u5 = X[(size_t)s5 * 64 + lane];
    unsigned short u6 = X[(size_t)s6 * 64 + lane];
    unsigned short u7 = X[(size_t)s7 * 64 + lane];
    a += bf2f(u0) + bf2f(u1) + bf2f(u2) + bf2f(u3);
    a += bf2f(u4) + bf2f(u5) + bf2f(u6) + bf2f(u7);
  }
  for (; e + 4 <= m; e += 4) {
    int s0 = p[e], s1 = p[e + 1], s2 = p[e + 2], s3 = p[e + 3];
    unsigned short u0 = X[(size_t)s0 * 64 + lane];
    unsigned short u1 = X[(size_t)s1 * 64 + lane];
    unsigned short u2 = X[(size_t)s2 * 64 + lane];
    unsigned short u3 = X[(size_t)s3 * 64 + lane];
    a += bf2f(u0) + bf2f(u1) + bf2f(u2) + bf2f(u3);
  }
  for (; e < m; ++e) a += bf2f(X[(size_t)p[e] * 64 + lane]);
  H[(size_t)wid * 64 + lane] = f2bf(a * norm[wid] + bias[lane]);
}

// ---------------- edge scoring: 16 lanes per query, bf16 rows ----------------
__global__ __launch_bounds__(256) void k_score(const unsigned short* __restrict__ H,
                                               const int* __restrict__ qs,
                                               const int* __restrict__ qd,
                                               float* __restrict__ out, int q) {
  int t = blockIdx.x * 256 + threadIdx.x;
  int sub = t & 15;
  int q0 = t >> 4;
  float p = 0.f;
  if (q0 < q) {
    int s = qs[q0], d = qd[q0];
    const uint2* Hu = (const uint2*)H;
    uint2 a = Hu[(size_t)s * 16 + sub];
    uint2 b = Hu[(size_t)d * 16 + sub];
    p = bfLo(a.x) * bfLo(b.x) + bfHi(a.x) * bfHi(b.x) +
        bfLo(a.y) * bfLo(b.y) + bfHi(a.y) * bfHi(b.y);
  }
  p += __shfl_xor(p, 1);
  p += __shfl_xor(p, 2);
  p += __shfl_xor(p, 4);
  p += __shfl_xor(p, 8);
  if (sub == 0 && q0 < q) out[q0] = 1.f / (1.f + expf(-p));
}

extern "C" void kernel_launch(void* const* d_in, const int* in_sizes, int n_in,
                              void* d_out, int out_size, void* d_ws, size_t ws_size,
                              hipStream_t stream) {
  const float* feat = (const float*)d_in[0];
  const int* esrc   = (const int*)d_in[1];
  const int* edst   = (const int*)d_in[2];
  const int* qsrc   = (const int*)d_in[3];
  const int* qdst   = (const int*)d_in[4];
  const float* W1   = (const float*)d_in[5];
  const float* b1   = (const float*)d_in[6];
  const float* W2   = (const float*)d_in[7];
  const float* b2   = (const float*)d_in[8];
  float* out = (float*)d_out;

  const int N = in_sizes[0] / 128;
  const int E = in_sizes[1];
  const int Q = in_sizes[3];

  const int G = 256;
  const int NB = (N + 255) >> 8;
  const int chunk = (E + G - 1) / G;
  const int lenS = NB * G;
  const int gScan = lenS / 256;

  char* w = (char*)d_ws;
  size_t o = 0;
  unsigned short* X1 = (unsigned short*)(w + o); o += align256((size_t)N * 128 * 2);
  unsigned short* X2 = (unsigned short*)(w + o); o += align256((size_t)N * 64 * 2);
  unsigned short* H2 = (unsigned short*)(w + o); o += align256((size_t)N * 64 * 2);
  int* cntIn = (int*)(w + o);       o += align256((size_t)N * 4);
  float* normOut = (float*)(w + o); o += align256((size_t)N * 4);
  float* normIn = (float*)(w + o);  o += align256((size_t)N * 4);
  int* offs = (int*)(w + o);        o += align256((size_t)N * 4);
  int* blkD = (int*)(w + o);        o += align256((size_t)lenS * 4);
  int* blkS = (int*)(w + o);        o += align256((size_t)lenS * 4);
  int* scD = (int*)(w + o);         o += align256((size_t)lenS * 4);
  int* scS = (int*)(w + o);         o += align256((size_t)lenS * 4);
  int* bsums = (int*)(w + o);       o += align256((size_t)4096);
  unsigned short* W1t = (unsigned short*)(w + o); o += align256((size_t)128 * 128 * 2);
  unsigned short* W2t = (unsigned short*)(w + o); o += align256((size_t)64 * 128 * 2);
  unsigned int* pairs = (unsigned int*)(w + o); o += align256((size_t)E * 4);
  unsigned int* keys = (unsigned int*)(w + o); o += align256((size_t)E * 4);
  int* csr = (int*)(w + o);         o += align256((size_t)E * 4);

  // weight prep (bf16 transposed)
  k_prep<<<64, 256, 0, stream>>>(W1, W2, W1t, W2t);

  // graph build (no global atomics)
  k_coarse_count<<<G, 256, 0, stream>>>(esrc, edst, E, chunk, NB, G, blkD, blkS);
  k_scan1<<<gScan, 256, 0, stream>>>(blkD, scD, bsums, lenS);
  k_scan2<<<1, 512, 0, stream>>>(bsums, gScan);
  k_scan3b<<<gScan, 256, 0, stream>>>(scD, bsums, lenS);
  k_scan1<<<gScan, 256, 0, stream>>>(blkS, scS, bsums, lenS);
  k_scan2<<<1, 512, 0, stream>>>(bsums, gScan);
  k_scan3b<<<gScan, 256, 0, stream>>>(scS, bsums, lenS);
  k_coarse_scatter<<<G, 256, 0, stream>>>(esrc, edst, E, chunk, NB, G, scD, scS, pairs, keys);
  k_fine_dst<<<NB, 256, 0, stream>>>(pairs, scD, G, E, N, NB, cntIn, normIn, offs, csr);
  k_fine_src<<<NB, 256, 0, stream>>>(keys, scS, G, E, N, NB, normOut);

  const int gRows = (N + 63) / 64;
  // layer 1 GEMM: X1 = (feat*normOut)@W1                                  [bf16]
  k_mgemm<128, float><<<gRows, 256, 0, stream>>>(feat, normOut, W1t, X1, N);
  // fused: H1 = relu(agg(X1)*normIn + b1);  X2 = (H1*normOut)@W2          [bf16]
  k_agg1_fused<<<gRows, 256, 0, stream>>>(X1, csr, offs, cntIn, normIn, normOut,
                                          b1, W2t, X2, N);
  // layer 2 agg: H2 = agg(X2)*normIn + b2                                 [bf16]
  k_agg64<<<(N + 3) / 4, 256, 0, stream>>>(X2, csr, offs, cntIn, normIn, b2, H2, N);
  // scoring
  k_score<<<((Q * 16) + 255) / 256, 256, 0, stream>>>(H2, qsrc, qdst, out, Q);
}

// Round 7
// 355.145 us; speedup vs baseline: 1.1577x; 1.1577x over previous
//
#include <hip/hip_runtime.h>
#include <math.h>

static inline size_t align256(size_t x) { return (x + 255) & ~(size_t)255; }

typedef __attribute__((ext_vector_type(8))) short bf16x8;
typedef __attribute__((ext_vector_type(4))) float f32x4;

// ---- bf16 helpers (fp32 accumulate everywhere; bf16 is storage only) ----
__device__ inline float bfLo(unsigned int u) {
  union { unsigned int i; float f; } v; v.i = u << 16; return v.f;
}
__device__ inline float bfHi(unsigned int u) {
  union { unsigned int i; float f; } v; v.i = u & 0xffff0000u; return v.f;
}
__device__ inline float bf2f(unsigned short u) {
  union { unsigned int i; float f; } v; v.i = ((unsigned int)u) << 16; return v.f;
}
__device__ inline unsigned short f2bf(float f) {
  union { float f; unsigned int i; } v; v.f = f;
  unsigned int r = v.i + 0x7FFF + ((v.i >> 16) & 1);  // RNE
  return (unsigned short)(r >> 16);
}
__device__ inline unsigned int packbf(float lo, float hi) {
  return ((unsigned int)f2bf(hi) << 16) | f2bf(lo);
}

// ============ graph build: two-level LDS-privatized binning ============
// blkD/blkS and scD/scS are halves of single arrays so one scan chain covers both.
__global__ __launch_bounds__(256) void k_coarse_count(const int* __restrict__ esrc,
                                                      const int* __restrict__ edst,
                                                      int E, int chunk, int NB, int G,
                                                      int* __restrict__ blkD,
                                                      int* __restrict__ blkS) {
  __shared__ int hD[512], hS[512];
  int blk = blockIdx.x, tid = threadIdx.x;
  for (int i = tid; i < NB; i += 256) { hD[i] = 0; hS[i] = 0; }
  __syncthreads();
  int s0 = blk * chunk, s1 = min(E, s0 + chunk);
  for (int e = s0 + tid; e < s1; e += 256) {
    atomicAdd(&hD[edst[e] >> 8], 1);
    atomicAdd(&hS[esrc[e] >> 8], 1);
  }
  __syncthreads();
  for (int i = tid; i < NB; i += 256) {
    blkD[i * G + blk] = hD[i];
    blkS[i * G + blk] = hS[i];
  }
}

__global__ __launch_bounds__(256) void k_scan1(const int* __restrict__ in,
                                               int* __restrict__ out,
                                               int* __restrict__ bsums, int n) {
  __shared__ int s[256];
  int tid = threadIdx.x, gid = blockIdx.x * 256 + tid;
  int v = (gid < n) ? in[gid] : 0;
  s[tid] = v; __syncthreads();
  for (int o = 1; o < 256; o <<= 1) {
    int t = (tid >= o) ? s[tid - o] : 0;
    __syncthreads();
    s[tid] += t;
    __syncthreads();
  }
  if (gid < n) out[gid] = s[tid] - v;
  if (tid == 255) bsums[blockIdx.x] = s[255];
}

// grid = 2: block b scans bsums[b*nb .. b*nb+nb) independently (D half, S half)
__global__ __launch_bounds__(512) void k_scan2(int* __restrict__ bsums, int nb) {
  __shared__ int s[512];
  int tid = threadIdx.x;
  int* base = bsums + blockIdx.x * nb;
  int v = (tid < nb) ? base[tid] : 0;
  s[tid] = v; __syncthreads();
  for (int o = 1; o < 512; o <<= 1) {
    int t = (tid >= o) ? s[tid - o] : 0;
    __syncthreads();
    s[tid] += t;
    __syncthreads();
  }
  if (tid < nb) base[tid] = s[tid] - v;
}

__global__ __launch_bounds__(256) void k_scan3b(int* __restrict__ arr,
                                                const int* __restrict__ bsums, int n) {
  int gid = blockIdx.x * 256 + threadIdx.x;
  if (gid < n) arr[gid] += bsums[blockIdx.x];
}

// P3: packed scatter. pair = (src<<8)|(dst&255): src<2^17 fits, dst fine index 8b.
__global__ __launch_bounds__(256) void k_coarse_scatter(const int* __restrict__ esrc,
                                                        const int* __restrict__ edst,
                                                        int E, int chunk, int NB, int G,
                                                        const int* __restrict__ scD,
                                                        const int* __restrict__ scS,
                                                        unsigned int* __restrict__ pairs,
                                                        unsigned int* __restrict__ keys) {
  __shared__ int cD[512], cS[512];
  int blk = blockIdx.x, tid = threadIdx.x;
  for (int i = tid; i < NB; i += 256) {
    cD[i] = scD[i * G + blk];
    cS[i] = scS[i * G + blk];
  }
  __syncthreads();
  int s0 = blk * chunk, s1 = min(E, s0 + chunk);
  for (int e = s0 + tid; e < s1; e += 256) {
    int s = esrc[e], d = edst[e];
    int pd = atomicAdd(&cD[d >> 8], 1);
    pairs[pd] = ((unsigned)s << 8) | ((unsigned)d & 255u);
    int ps = atomicAdd(&cS[s >> 8], 1);
    keys[ps] = (unsigned)s;
  }
}

// merged fine pass: blocks [0,NB) = dst buckets (csr build), [NB,2NB) = src buckets (normOut)
__global__ __launch_bounds__(256) void k_fine(const unsigned int* __restrict__ pairs,
                                              const unsigned int* __restrict__ keys,
                                              const int* __restrict__ scD,
                                              const int* __restrict__ scS,
                                              int G, int E, int N, int NB,
                                              int* __restrict__ cntIn,
                                              float* __restrict__ normIn,
                                              int* __restrict__ offs,
                                              int* __restrict__ csr,
                                              float* __restrict__ normOut) {
  __shared__ int hist[256], scn[256], cur[256];
  int tid = threadIdx.x;
  if (blockIdx.x >= (unsigned)NB) {   // src half: degree -> normOut
    int b = blockIdx.x - NB;
    int bstart = scS[b * G];
    int bend = (b + 1 < NB) ? scS[(b + 1) * G] : E;
    hist[tid] = 0;
    __syncthreads();
    for (int e = bstart + tid; e < bend; e += 256)
      atomicAdd(&hist[keys[e] & 255u], 1);
    __syncthreads();
    int node = b * 256 + tid;
    if (node < N) normOut[node] = rsqrtf((float)max(hist[tid], 1));
    return;
  }
  int b = blockIdx.x;
  int bstart = scD[b * G];
  int bend = (b + 1 < NB) ? scD[(b + 1) * G] : E;
  hist[tid] = 0;
  __syncthreads();
  for (int e = bstart + tid; e < bend; e += 256)
    atomicAdd(&hist[pairs[e] & 255u], 1);
  __syncthreads();
  int v = hist[tid];
  scn[tid] = v;
  __syncthreads();
  for (int o = 1; o < 256; o <<= 1) {
    int t = (tid >= o) ? scn[tid - o] : 0;
    __syncthreads();
    scn[tid] += t;
    __syncthreads();
  }
  int excl = scn[tid] - v;
  cur[tid] = excl;
  int node = b * 256 + tid;
  if (node < N) {
    cntIn[node] = v;
    normIn[node] = rsqrtf((float)max(v, 1));
    offs[node] = bstart + excl;
  }
  __syncthreads();
  for (int e = bstart + tid; e < bend; e += 256) {
    unsigned int u = pairs[e];
    int p = bstart + atomicAdd(&cur[u & 255u], 1);
    csr[p] = (int)(u >> 8);
  }
}

// ---------------- weight prep: W[K x C] fp32 -> Wt[C x K] bf16 (n-major) ----------------
__global__ __launch_bounds__(256) void k_prep(const float* __restrict__ W1,
                                              const float* __restrict__ W2,
                                              unsigned short* __restrict__ W1t,
                                              unsigned short* __restrict__ W2t) {
  int t = blockIdx.x * 256 + threadIdx.x;
  int stride = gridDim.x * 256;
  for (int i = t; i < 128 * 128; i += stride) {
    int nn = i >> 7, kk = i & 127;
    W1t[i] = f2bf(W1[kk * 128 + nn]);
  }
  for (int i = t; i < 64 * 128; i += stride) {
    int nn = i >> 7, kk = i & 127;
    W2t[i] = f2bf(W2[kk * 64 + nn]);
  }
}

// ---------------- MFMA GEMM: out[n x C](bf16) = diag(scale)*A[n x 128] @ W[128 x C] ----------------
template <int C, typename TA>
__global__ __launch_bounds__(256) void k_mgemm(const TA* __restrict__ A,
                                               const float* __restrict__ scale,
                                               const unsigned short* __restrict__ Wt,
                                               unsigned short* __restrict__ out, int n) {
  constexpr int KP = 136;
  constexpr int NCH = C / 16;
  __shared__ __align__(16) unsigned short Al[64 * KP];
  __shared__ __align__(16) unsigned short Wl[C * KP];
  int tid = threadIdx.x;
  int r0 = blockIdx.x * 64;

  {
    const uint4* Wg = (const uint4*)Wt;
    uint4* Wd = (uint4*)Wl;
    for (int idx = tid; idx < C * 16; idx += 256) {
      int row = idx >> 4, seg = idx & 15;
      Wd[row * 17 + seg] = Wg[idx];
    }
  }
  {
    int seg = tid & 7;
    for (int it = 0; it < 2; ++it) {
      int row = (tid >> 3) + it * 32;
      int g = r0 + row;
      float v[16];
      if (g < n) {
        float sc = scale[g];
        if constexpr (sizeof(TA) == 4) {
          const float4* Ag = (const float4*)((const float*)A + (size_t)g * 128);
#pragma unroll
          for (int j = 0; j < 4; ++j) {
            float4 f = Ag[seg * 4 + j];
            v[j * 4 + 0] = f.x * sc; v[j * 4 + 1] = f.y * sc;
            v[j * 4 + 2] = f.z * sc; v[j * 4 + 3] = f.w * sc;
          }
        } else {
          const uint4* Ag = (const uint4*)((const unsigned short*)A + (size_t)g * 128);
#pragma unroll
          for (int j = 0; j < 2; ++j) {
            uint4 u = Ag[seg * 2 + j];
            v[j * 8 + 0] = bfLo(u.x) * sc; v[j * 8 + 1] = bfHi(u.x) * sc;
            v[j * 8 + 2] = bfLo(u.y) * sc; v[j * 8 + 3] = bfHi(u.y) * sc;
            v[j * 8 + 4] = bfLo(u.z) * sc; v[j * 8 + 5] = bfHi(u.z) * sc;
            v[j * 8 + 6] = bfLo(u.w) * sc; v[j * 8 + 7] = bfHi(u.w) * sc;
          }
        }
      } else {
#pragma unroll
        for (int j = 0; j < 16; ++j) v[j] = 0.f;
      }
      uint4* dst = (uint4*)(Al + row * KP + seg * 16);
      dst[0] = make_uint4(packbf(v[0], v[1]), packbf(v[2], v[3]),
                          packbf(v[4], v[5]), packbf(v[6], v[7]));
      dst[1] = make_uint4(packbf(v[8], v[9]), packbf(v[10], v[11]),
                          packbf(v[12], v[13]), packbf(v[14], v[15]));
    }
  }
  __syncthreads();

  int lane = tid & 63;
  int w = tid >> 6;
  int quad = lane >> 4, m16 = lane & 15;
  f32x4 acc[NCH];
#pragma unroll
  for (int c = 0; c < NCH; ++c) acc[c] = (f32x4){0.f, 0.f, 0.f, 0.f};

#pragma unroll
  for (int kc = 0; kc < 4; ++kc) {
    int ko = kc * 32 + quad * 8;
    bf16x8 a = *(const bf16x8*)(Al + (w * 16 + m16) * KP + ko);
#pragma unroll
    for (int c = 0; c < NCH; ++c) {
      bf16x8 b = *(const bf16x8*)(Wl + (c * 16 + m16) * KP + ko);
      acc[c] = __builtin_amdgcn_mfma_f32_16x16x32_bf16(a, b, acc[c], 0, 0, 0);
    }
  }

#pragma unroll
  for (int c = 0; c < NCH; ++c)
#pragma unroll
    for (int r = 0; r < 4; ++r) {
      int g = r0 + w * 16 + quad * 4 + r;
      if (g < n) out[(size_t)g * C + c * 16 + m16] = f2bf(acc[c][r]);
    }
}

// ---------------- aggregation: one wave per dst node ----------------
// R6 post-mortem: gather is latency-bound; this version loads up to 64 neighbor
// indices in ONE coalesced load and broadcasts them via __shfl (VALU, no memory),
// so row loads issue back-to-back with 16 in flight (vs 4 + serial csr loads).
__global__ __launch_bounds__(256) void k_agg128_relu(const unsigned short* __restrict__ X,
                                                     const int* __restrict__ csr,
                                                     const int* __restrict__ offs,
                                                     const int* __restrict__ cnt,
                                                     const float* __restrict__ norm,
                                                     const float* __restrict__ bias,
                                                     unsigned short* __restrict__ H, int n) {
  int wid = blockIdx.x * 4 + (threadIdx.x >> 6);
  if (wid >= n) return;
  int lane = threadIdx.x & 63;
  int start = offs[wid], m = cnt[wid];
  const int* p = csr + start;
  const unsigned int* Xu = (const unsigned int*)X;  // row stride 64 uints
  float ax = 0.f, ay = 0.f;
  for (int c0 = 0; c0 < m; c0 += 64) {
    int take = min(64, m - c0);
    int iv = p[c0 + ((lane < take) ? lane : take - 1)];   // one coalesced load
    int e = 0;
    for (; e + 16 <= take; e += 16) {
      int ss[16]; unsigned int uu[16];
#pragma unroll
      for (int j = 0; j < 16; ++j) ss[j] = __shfl(iv, e + j);
#pragma unroll
      for (int j = 0; j < 16; ++j) uu[j] = Xu[(size_t)ss[j] * 64 + lane];
#pragma unroll
      for (int j = 0; j < 16; ++j) { ax += bfLo(uu[j]); ay += bfHi(uu[j]); }
    }
    for (; e + 4 <= take; e += 4) {
      int ss[4]; unsigned int uu[4];
#pragma unroll
      for (int j = 0; j < 4; ++j) ss[j] = __shfl(iv, e + j);
#pragma unroll
      for (int j = 0; j < 4; ++j) uu[j] = Xu[(size_t)ss[j] * 64 + lane];
#pragma unroll
      for (int j = 0; j < 4; ++j) { ax += bfLo(uu[j]); ay += bfHi(uu[j]); }
    }
    for (; e < take; ++e) {
      unsigned int u = Xu[(size_t)__shfl(iv, e) * 64 + lane];
      ax += bfLo(u); ay += bfHi(u);
    }
  }
  float nm = norm[wid];
  float2 b = ((const float2*)bias)[lane];
  float ox = fmaxf(ax * nm + b.x, 0.f);
  float oy = fmaxf(ay * nm + b.y, 0.f);
  ((unsigned int*)H)[(size_t)wid * 64 + lane] = packbf(ox, oy);
}

__global__ __launch_bounds__(256) void k_agg64(const unsigned short* __restrict__ X,
                                               const int* __restrict__ csr,
                                               const int* __restrict__ offs,
                                               const int* __restrict__ cnt,
                                               const float* __restrict__ norm,
                                               const float* __restrict__ bias,
                                               unsigned short* __restrict__ H, int n) {
  int wid = blockIdx.x * 4 + (threadIdx.x >> 6);
  if (wid >= n) return;
  int lane = threadIdx.x & 63;
  int start = offs[wid], m = cnt[wid];
  const int* p = csr + start;
  float a = 0.f;
  for (int c0 = 0; c0 < m; c0 += 64) {
    int take = min(64, m - c0);
    int iv = p[c0 + ((lane < take) ? lane : take - 1)];
    int e = 0;
    for (; e + 16 <= take; e += 16) {
      int ss[16]; unsigned short uu[16];
#pragma unroll
      for (int j = 0; j < 16; ++j) ss[j] = __shfl(iv, e + j);
#pragma unroll
      for (int j = 0; j < 16; ++j) uu[j] = X[(size_t)ss[j] * 64 + lane];
#pragma unroll
      for (int j = 0; j < 16; ++j) a += bf2f(uu[j]);
    }
    for (; e + 4 <= take; e += 4) {
      int ss[4]; unsigned short uu[4];
#pragma unroll
      for (int j = 0; j < 4; ++j) ss[j] = __shfl(iv, e + j);
#pragma unroll
      for (int j = 0; j < 4; ++j) uu[j] = X[(size_t)ss[j] * 64 + lane];
#pragma unroll
      for (int j = 0; j < 4; ++j) a += bf2f(uu[j]);
    }
    for (; e < take; ++e) a += bf2f(X[(size_t)__shfl(iv, e) * 64 + lane]);
  }
  H[(size_t)wid * 64 + lane] = f2bf(a * norm[wid] + bias[lane]);
}

// ---------------- edge scoring: 16 lanes per query, bf16 rows ----------------
__global__ __launch_bounds__(256) void k_score(const unsigned short* __restrict__ H,
                                               const int* __restrict__ qs,
                                               const int* __restrict__ qd,
                                               float* __restrict__ out, int q) {
  int t = blockIdx.x * 256 + threadIdx.x;
  int sub = t & 15;
  int q0 = t >> 4;
  float p = 0.f;
  if (q0 < q) {
    int s = qs[q0], d = qd[q0];
    const uint2* Hu = (const uint2*)H;
    uint2 a = Hu[(size_t)s * 16 + sub];
    uint2 b = Hu[(size_t)d * 16 + sub];
    p = bfLo(a.x) * bfLo(b.x) + bfHi(a.x) * bfHi(b.x) +
        bfLo(a.y) * bfLo(b.y) + bfHi(a.y) * bfHi(b.y);
  }
  p += __shfl_xor(p, 1);
  p += __shfl_xor(p, 2);
  p += __shfl_xor(p, 4);
  p += __shfl_xor(p, 8);
  if (sub == 0 && q0 < q) out[q0] = 1.f / (1.f + expf(-p));
}

extern "C" void kernel_launch(void* const* d_in, const int* in_sizes, int n_in,
                              void* d_out, int out_size, void* d_ws, size_t ws_size,
                              hipStream_t stream) {
  const float* feat = (const float*)d_in[0];
  const int* esrc   = (const int*)d_in[1];
  const int* edst   = (const int*)d_in[2];
  const int* qsrc   = (const int*)d_in[3];
  const int* qdst   = (const int*)d_in[4];
  const float* W1   = (const float*)d_in[5];
  const float* b1   = (const float*)d_in[6];
  const float* W2   = (const float*)d_in[7];
  const float* b2   = (const float*)d_in[8];
  float* out = (float*)d_out;

  const int N = in_sizes[0] / 128;
  const int E = in_sizes[1];
  const int Q = in_sizes[3];

  const int G = 256;
  const int NB = (N + 255) >> 8;
  const int chunk = (E + G - 1) / G;
  const int lenS = NB * G;
  const int gScan = lenS / 256;        // blocks per half

  char* w = (char*)d_ws;
  size_t o = 0;
  unsigned short* X1 = (unsigned short*)(w + o); o += align256((size_t)N * 128 * 2);
  unsigned short* X2 = (unsigned short*)(w + o); o += align256((size_t)N * 64 * 2);
  unsigned short* H2 = (unsigned short*)(w + o); o += align256((size_t)N * 64 * 2);
  int* cntIn = (int*)(w + o);       o += align256((size_t)N * 4);
  float* normOut = (float*)(w + o); o += align256((size_t)N * 4);
  float* normIn = (float*)(w + o);  o += align256((size_t)N * 4);
  int* offs = (int*)(w + o);        o += align256((size_t)N * 4);
  int* blk = (int*)(w + o);         o += align256((size_t)lenS * 8);   // D half + S half
  int* sc = (int*)(w + o);          o += align256((size_t)lenS * 8);   // D half + S half
  int* bsums = (int*)(w + o);       o += align256((size_t)8192);
  unsigned short* W1t = (unsigned short*)(w + o); o += align256((size_t)128 * 128 * 2);
  unsigned short* W2t = (unsigned short*)(w + o); o += align256((size_t)64 * 128 * 2);
  unsigned int* pairs = (unsigned int*)(w + o); o += align256((size_t)E * 4);
  unsigned int* keys = (unsigned int*)(w + o); o += align256((size_t)E * 4);
  int* csr = (int*)(w + o);         o += align256((size_t)E * 4);

  int* blkD = blk;        int* blkS = blk + lenS;
  int* scD = sc;          int* scS = sc + lenS;

  // weight prep (bf16 transposed)
  k_prep<<<64, 256, 0, stream>>>(W1, W2, W1t, W2t);

  // graph build (no global atomics); one scan chain covers both halves
  k_coarse_count<<<G, 256, 0, stream>>>(esrc, edst, E, chunk, NB, G, blkD, blkS);
  k_scan1<<<2 * gScan, 256, 0, stream>>>(blk, sc, bsums, 2 * lenS);
  k_scan2<<<2, 512, 0, stream>>>(bsums, gScan);
  k_scan3b<<<2 * gScan, 256, 0, stream>>>(sc, bsums, 2 * lenS);
  k_coarse_scatter<<<G, 256, 0, stream>>>(esrc, edst, E, chunk, NB, G, scD, scS, pairs, keys);
  k_fine<<<2 * NB, 256, 0, stream>>>(pairs, keys, scD, scS, G, E, N, NB,
                                     cntIn, normIn, offs, csr, normOut);

  const int gRows = (N + 63) / 64;
  // layer 1: X1 = (feat*normOut)@W1 ; H1 = relu(agg(X1)*normIn + b1)    [bf16]
  k_mgemm<128, float><<<gRows, 256, 0, stream>>>(feat, normOut, W1t, X1, N);
  k_agg128_relu<<<(N + 3) / 4, 256, 0, stream>>>(X1, csr, offs, cntIn, normIn, b1, X2, N);
  // layer 2: X2b = (H1*normOut)@W2 ; H2 = agg(X2b)*normIn + b2          [bf16]
  k_mgemm<64, unsigned short><<<gRows, 256, 0, stream>>>(X2, normOut, W2t, X1, N);
  k_agg64<<<(N + 3) / 4, 256, 0, stream>>>(X1, csr, offs, cntIn, normIn, b2, H2, N);
  // scoring
  k_score<<<((Q * 16) + 255) / 256, 256, 0, stream>>>(H2, qsrc, qdst, out, Q);
}

// Round 8
// 325.288 us; speedup vs baseline: 1.2639x; 1.0918x over previous
//
#include <hip/hip_runtime.h>
#include <math.h>

static inline size_t align256(size_t x) { return (x + 255) & ~(size_t)255; }

typedef __attribute__((ext_vector_type(8))) short bf16x8;
typedef __attribute__((ext_vector_type(4))) float f32x4;

// ---- bf16 helpers (fp32 accumulate everywhere; bf16 is storage only) ----
__device__ inline float bfLo(unsigned int u) {
  union { unsigned int i; float f; } v; v.i = u << 16; return v.f;
}
__device__ inline float bfHi(unsigned int u) {
  union { unsigned int i; float f; } v; v.i = u & 0xffff0000u; return v.f;
}
__device__ inline float bf2f(unsigned short u) {
  union { unsigned int i; float f; } v; v.i = ((unsigned int)u) << 16; return v.f;
}
__device__ inline unsigned short f2bf(float f) {
  union { float f; unsigned int i; } v; v.f = f;
  unsigned int r = v.i + 0x7FFF + ((v.i >> 16) & 1);  // RNE
  return (unsigned short)(r >> 16);
}
__device__ inline unsigned int packbf(float lo, float hi) {
  return ((unsigned int)f2bf(hi) << 16) | f2bf(lo);
}

// ============ graph build: two-level LDS-privatized binning ============
__global__ __launch_bounds__(256) void k_coarse_count(const int* __restrict__ esrc,
                                                      const int* __restrict__ edst,
                                                      int E, int chunk, int NB, int G,
                                                      int* __restrict__ blkD,
                                                      int* __restrict__ blkS) {
  __shared__ int hD[512], hS[512];
  int blk = blockIdx.x, tid = threadIdx.x;
  for (int i = tid; i < NB; i += 256) { hD[i] = 0; hS[i] = 0; }
  __syncthreads();
  int s0 = blk * chunk, s1 = min(E, s0 + chunk);
  for (int e = s0 + tid; e < s1; e += 256) {
    atomicAdd(&hD[edst[e] >> 8], 1);
    atomicAdd(&hS[esrc[e] >> 8], 1);
  }
  __syncthreads();
  for (int i = tid; i < NB; i += 256) {
    blkD[i * G + blk] = hD[i];
    blkS[i * G + blk] = hS[i];
  }
}

__global__ __launch_bounds__(256) void k_scan1(const int* __restrict__ in,
                                               int* __restrict__ out,
                                               int* __restrict__ bsums, int n) {
  __shared__ int s[256];
  int tid = threadIdx.x, gid = blockIdx.x * 256 + tid;
  int v = (gid < n) ? in[gid] : 0;
  s[tid] = v; __syncthreads();
  for (int o = 1; o < 256; o <<= 1) {
    int t = (tid >= o) ? s[tid - o] : 0;
    __syncthreads();
    s[tid] += t;
    __syncthreads();
  }
  if (gid < n) out[gid] = s[tid] - v;
  if (tid == 255) bsums[blockIdx.x] = s[255];
}

// grid = 2: block b scans bsums[b*nb .. b*nb+nb) independently (D half, S half)
__global__ __launch_bounds__(512) void k_scan2(int* __restrict__ bsums, int nb) {
  __shared__ int s[512];
  int tid = threadIdx.x;
  int* base = bsums + blockIdx.x * nb;
  int v = (tid < nb) ? base[tid] : 0;
  s[tid] = v; __syncthreads();
  for (int o = 1; o < 512; o <<= 1) {
    int t = (tid >= o) ? s[tid - o] : 0;
    __syncthreads();
    s[tid] += t;
    __syncthreads();
  }
  if (tid < nb) base[tid] = s[tid] - v;
}

__global__ __launch_bounds__(256) void k_scan3b(int* __restrict__ arr,
                                                const int* __restrict__ bsums, int n) {
  int gid = blockIdx.x * 256 + threadIdx.x;
  if (gid < n) arr[gid] += bsums[blockIdx.x];
}

// P3: packed scatter. pair = (src<<8)|(dst&255): src<2^17 fits, dst fine index 8b.
__global__ __launch_bounds__(256) void k_coarse_scatter(const int* __restrict__ esrc,
                                                        const int* __restrict__ edst,
                                                        int E, int chunk, int NB, int G,
                                                        const int* __restrict__ scD,
                                                        const int* __restrict__ scS,
                                                        unsigned int* __restrict__ pairs,
                                                        unsigned int* __restrict__ keys) {
  __shared__ int cD[512], cS[512];
  int blk = blockIdx.x, tid = threadIdx.x;
  for (int i = tid; i < NB; i += 256) {
    cD[i] = scD[i * G + blk];
    cS[i] = scS[i * G + blk];
  }
  __syncthreads();
  int s0 = blk * chunk, s1 = min(E, s0 + chunk);
  for (int e = s0 + tid; e < s1; e += 256) {
    int s = esrc[e], d = edst[e];
    int pd = atomicAdd(&cD[d >> 8], 1);
    pairs[pd] = ((unsigned)s << 8) | ((unsigned)d & 255u);
    int ps = atomicAdd(&cS[s >> 8], 1);
    keys[ps] = (unsigned)s;
  }
}

// merged fine pass: blocks [0,NB) = dst buckets (csr build), [NB,2NB) = src buckets (normOut)
__global__ __launch_bounds__(256) void k_fine(const unsigned int* __restrict__ pairs,
                                              const unsigned int* __restrict__ keys,
                                              const int* __restrict__ scD,
                                              const int* __restrict__ scS,
                                              int G, int E, int N, int NB,
                                              int* __restrict__ cntIn,
                                              float* __restrict__ normIn,
                                              int* __restrict__ offs,
                                              int* __restrict__ csr,
                                              float* __restrict__ normOut) {
  __shared__ int hist[256], scn[256], cur[256];
  int tid = threadIdx.x;
  if (blockIdx.x >= (unsigned)NB) {   // src half: degree -> normOut
    int b = blockIdx.x - NB;
    int bstart = scS[b * G];
    int bend = (b + 1 < NB) ? scS[(b + 1) * G] : E;
    hist[tid] = 0;
    __syncthreads();
    for (int e = bstart + tid; e < bend; e += 256)
      atomicAdd(&hist[keys[e] & 255u], 1);
    __syncthreads();
    int node = b * 256 + tid;
    if (node < N) normOut[node] = rsqrtf((float)max(hist[tid], 1));
    return;
  }
  int b = blockIdx.x;
  int bstart = scD[b * G];
  int bend = (b + 1 < NB) ? scD[(b + 1) * G] : E;
  hist[tid] = 0;
  __syncthreads();
  for (int e = bstart + tid; e < bend; e += 256)
    atomicAdd(&hist[pairs[e] & 255u], 1);
  __syncthreads();
  int v = hist[tid];
  scn[tid] = v;
  __syncthreads();
  for (int o = 1; o < 256; o <<= 1) {
    int t = (tid >= o) ? scn[tid - o] : 0;
    __syncthreads();
    scn[tid] += t;
    __syncthreads();
  }
  int excl = scn[tid] - v;
  cur[tid] = excl;
  int node = b * 256 + tid;
  if (node < N) {
    cntIn[node] = v;
    normIn[node] = rsqrtf((float)max(v, 1));
    offs[node] = bstart + excl;
  }
  __syncthreads();
  for (int e = bstart + tid; e < bend; e += 256) {
    unsigned int u = pairs[e];
    int p = bstart + atomicAdd(&cur[u & 255u], 1);
    csr[p] = (int)(u >> 8);
  }
}

// ---------------- weight prep: W[K x C] fp32 -> Wt[C x K] bf16 (n-major) ----------------
__global__ __launch_bounds__(256) void k_prep(const float* __restrict__ W1,
                                              const float* __restrict__ W2,
                                              unsigned short* __restrict__ W1t,
                                              unsigned short* __restrict__ W2t) {
  int t = blockIdx.x * 256 + threadIdx.x;
  int stride = gridDim.x * 256;
  for (int i = t; i < 128 * 128; i += stride) {
    int nn = i >> 7, kk = i & 127;
    W1t[i] = f2bf(W1[kk * 128 + nn]);
  }
  for (int i = t; i < 64 * 128; i += stride) {
    int nn = i >> 7, kk = i & 127;
    W2t[i] = f2bf(W2[kk * 64 + nn]);
  }
}

// ---------------- MFMA GEMM: out[n x C](bf16) = diag(scale)*A[n x 128] @ W[128 x C] ----------------
template <int C, typename TA>
__global__ __launch_bounds__(256) void k_mgemm(const TA* __restrict__ A,
                                               const float* __restrict__ scale,
                                               const unsigned short* __restrict__ Wt,
                                               unsigned short* __restrict__ out, int n) {
  constexpr int KP = 136;
  constexpr int NCH = C / 16;
  __shared__ __align__(16) unsigned short Al[64 * KP];
  __shared__ __align__(16) unsigned short Wl[C * KP];
  int tid = threadIdx.x;
  int r0 = blockIdx.x * 64;

  {
    const uint4* Wg = (const uint4*)Wt;
    uint4* Wd = (uint4*)Wl;
    for (int idx = tid; idx < C * 16; idx += 256) {
      int row = idx >> 4, seg = idx & 15;
      Wd[row * 17 + seg] = Wg[idx];
    }
  }
  {
    int seg = tid & 7;
    for (int it = 0; it < 2; ++it) {
      int row = (tid >> 3) + it * 32;
      int g = r0 + row;
      float v[16];
      if (g < n) {
        float sc = scale[g];
        if constexpr (sizeof(TA) == 4) {
          const float4* Ag = (const float4*)((const float*)A + (size_t)g * 128);
#pragma unroll
          for (int j = 0; j < 4; ++j) {
            float4 f = Ag[seg * 4 + j];
            v[j * 4 + 0] = f.x * sc; v[j * 4 + 1] = f.y * sc;
            v[j * 4 + 2] = f.z * sc; v[j * 4 + 3] = f.w * sc;
          }
        } else {
          const uint4* Ag = (const uint4*)((const unsigned short*)A + (size_t)g * 128);
#pragma unroll
          for (int j = 0; j < 2; ++j) {
            uint4 u = Ag[seg * 2 + j];
            v[j * 8 + 0] = bfLo(u.x) * sc; v[j * 8 + 1] = bfHi(u.x) * sc;
            v[j * 8 + 2] = bfLo(u.y) * sc; v[j * 8 + 3] = bfHi(u.y) * sc;
            v[j * 8 + 4] = bfLo(u.z) * sc; v[j * 8 + 5] = bfHi(u.z) * sc;
            v[j * 8 + 6] = bfLo(u.w) * sc; v[j * 8 + 7] = bfHi(u.w) * sc;
          }
        }
      } else {
#pragma unroll
        for (int j = 0; j < 16; ++j) v[j] = 0.f;
      }
      uint4* dst = (uint4*)(Al + row * KP + seg * 16);
      dst[0] = make_uint4(packbf(v[0], v[1]), packbf(v[2], v[3]),
                          packbf(v[4], v[5]), packbf(v[6], v[7]));
      dst[1] = make_uint4(packbf(v[8], v[9]), packbf(v[10], v[11]),
                          packbf(v[12], v[13]), packbf(v[14], v[15]));
    }
  }
  __syncthreads();

  int lane = tid & 63;
  int w = tid >> 6;
  int quad = lane >> 4, m16 = lane & 15;
  f32x4 acc[NCH];
#pragma unroll
  for (int c = 0; c < NCH; ++c) acc[c] = (f32x4){0.f, 0.f, 0.f, 0.f};

#pragma unroll
  for (int kc = 0; kc < 4; ++kc) {
    int ko = kc * 32 + quad * 8;
    bf16x8 a = *(const bf16x8*)(Al + (w * 16 + m16) * KP + ko);
#pragma unroll
    for (int c = 0; c < NCH; ++c) {
      bf16x8 b = *(const bf16x8*)(Wl + (c * 16 + m16) * KP + ko);
      acc[c] = __builtin_amdgcn_mfma_f32_16x16x32_bf16(a, b, acc[c], 0, 0, 0);
    }
  }

#pragma unroll
  for (int c = 0; c < NCH; ++c)
#pragma unroll
    for (int r = 0; r < 4; ++r) {
      int g = r0 + w * 16 + quad * 4 + r;
      if (g < n) out[(size_t)g * C + c * 16 + m16] = f2bf(acc[c][r]);
    }
}

// ---------------- aggregation: one wave per dst node, multi-edge vectorized ----------------
// R7 post-mortem: gather ~half issue-bound. This version fetches 4 rows in
// parallel (16 lanes x uint4 = 256 B/row): per 16 edges a lane issues
// 4 shfl + 4 dwordx4 + 32 adds (vs 16+16+32). Cross-group combine: 2 shfl_xor.
__global__ __launch_bounds__(256) void k_agg128_relu(const unsigned short* __restrict__ X,
                                                     const int* __restrict__ csr,
                                                     const int* __restrict__ offs,
                                                     const int* __restrict__ cnt,
                                                     const float* __restrict__ norm,
                                                     const float* __restrict__ bias,
                                                     unsigned short* __restrict__ H, int n) {
  int wid = blockIdx.x * 4 + (threadIdx.x >> 6);
  if (wid >= n) return;
  int lane = threadIdx.x & 63;
  int sub = lane & 15;          // 16B segment within the 256B row
  int grp = lane >> 4;          // which of 4 concurrent edges
  int start = offs[wid], m = cnt[wid];
  const int* p = csr + start;
  const uint4* Xv = (const uint4*)X;  // row stride 16 uint4
  float a[8] = {0.f, 0.f, 0.f, 0.f, 0.f, 0.f, 0.f, 0.f};
  for (int c0 = 0; c0 < m; c0 += 64) {
    int take = min(64, m - c0);
    int iv = p[c0 + ((lane < take) ? lane : take - 1)];   // one coalesced load
    int e = 0;
    for (; e + 16 <= take; e += 16) {
      uint4 uu[4];
#pragma unroll
      for (int j = 0; j < 4; ++j) {
        int ss = __shfl(iv, e + j * 4 + grp);
        uu[j] = Xv[(size_t)ss * 16 + sub];
      }
#pragma unroll
      for (int j = 0; j < 4; ++j) {
        a[0] += bfLo(uu[j].x); a[1] += bfHi(uu[j].x);
        a[2] += bfLo(uu[j].y); a[3] += bfHi(uu[j].y);
        a[4] += bfLo(uu[j].z); a[5] += bfHi(uu[j].z);
        a[6] += bfLo(uu[j].w); a[7] += bfHi(uu[j].w);
      }
    }
    for (; e + 4 <= take; e += 4) {
      int ss = __shfl(iv, e + grp);
      uint4 u = Xv[(size_t)ss * 16 + sub];
      a[0] += bfLo(u.x); a[1] += bfHi(u.x);
      a[2] += bfLo(u.y); a[3] += bfHi(u.y);
      a[4] += bfLo(u.z); a[5] += bfHi(u.z);
      a[6] += bfLo(u.w); a[7] += bfHi(u.w);
    }
    int r = take - e;
    if (r > 0) {
      int ss = __shfl(iv, min(e + grp, take - 1));
      uint4 u = Xv[(size_t)ss * 16 + sub];
      if (grp < r) {
        a[0] += bfLo(u.x); a[1] += bfHi(u.x);
        a[2] += bfLo(u.y); a[3] += bfHi(u.y);
        a[4] += bfLo(u.z); a[5] += bfHi(u.z);
        a[6] += bfLo(u.w); a[7] += bfHi(u.w);
      }
    }
  }
#pragma unroll
  for (int k = 0; k < 8; ++k) {
    a[k] += __shfl_xor(a[k], 16);
    a[k] += __shfl_xor(a[k], 32);
  }
  float nm = norm[wid];
  const float4* bv = (const float4*)bias;     // cols sub*8 .. sub*8+7
  float4 b0 = bv[sub * 2], b1 = bv[sub * 2 + 1];
  if (grp == 0) {
    float o0 = fmaxf(a[0] * nm + b0.x, 0.f);
    float o1 = fmaxf(a[1] * nm + b0.y, 0.f);
    float o2 = fmaxf(a[2] * nm + b0.z, 0.f);
    float o3 = fmaxf(a[3] * nm + b0.w, 0.f);
    float o4 = fmaxf(a[4] * nm + b1.x, 0.f);
    float o5 = fmaxf(a[5] * nm + b1.y, 0.f);
    float o6 = fmaxf(a[6] * nm + b1.z, 0.f);
    float o7 = fmaxf(a[7] * nm + b1.w, 0.f);
    uint4 o = make_uint4(packbf(o0, o1), packbf(o2, o3),
                         packbf(o4, o5), packbf(o6, o7));
    ((uint4*)H)[(size_t)wid * 16 + sub] = o;
  }
}

// layer-2 aggregation: 8 edges in parallel (8 lanes x uint4 = 128 B row)
__global__ __launch_bounds__(256) void k_agg64(const unsigned short* __restrict__ X,
                                               const int* __restrict__ csr,
                                               const int* __restrict__ offs,
                                               const int* __restrict__ cnt,
                                               const float* __restrict__ norm,
                                               const float* __restrict__ bias,
                                               unsigned short* __restrict__ H, int n) {
  int wid = blockIdx.x * 4 + (threadIdx.x >> 6);
  if (wid >= n) return;
  int lane = threadIdx.x & 63;
  int sub = lane & 7;           // 16B segment within the 128B row
  int grp = lane >> 3;          // which of 8 concurrent edges
  int start = offs[wid], m = cnt[wid];
  const int* p = csr + start;
  const uint4* Xv = (const uint4*)X;  // row stride 8 uint4
  float a[8] = {0.f, 0.f, 0.f, 0.f, 0.f, 0.f, 0.f, 0.f};
  for (int c0 = 0; c0 < m; c0 += 64) {
    int take = min(64, m - c0);
    int iv = p[c0 + ((lane < take) ? lane : take - 1)];
    int e = 0;
    for (; e + 16 <= take; e += 16) {
      uint4 uu[2];
#pragma unroll
      for (int j = 0; j < 2; ++j) {
        int ss = __shfl(iv, e + j * 8 + grp);
        uu[j] = Xv[(size_t)ss * 8 + sub];
      }
#pragma unroll
      for (int j = 0; j < 2; ++j) {
        a[0] += bfLo(uu[j].x); a[1] += bfHi(uu[j].x);
        a[2] += bfLo(uu[j].y); a[3] += bfHi(uu[j].y);
        a[4] += bfLo(uu[j].z); a[5] += bfHi(uu[j].z);
        a[6] += bfLo(uu[j].w); a[7] += bfHi(uu[j].w);
      }
    }
    for (; e + 8 <= take; e += 8) {
      int ss = __shfl(iv, e + grp);
      uint4 u = Xv[(size_t)ss * 8 + sub];
      a[0] += bfLo(u.x); a[1] += bfHi(u.x);
      a[2] += bfLo(u.y); a[3] += bfHi(u.y);
      a[4] += bfLo(u.z); a[5] += bfHi(u.z);
      a[6] += bfLo(u.w); a[7] += bfHi(u.w);
    }
    int r = take - e;
    if (r > 0) {
      int ss = __shfl(iv, min(e + grp, take - 1));
      uint4 u = Xv[(size_t)ss * 8 + sub];
      if (grp < r) {
        a[0] += bfLo(u.x); a[1] += bfHi(u.x);
        a[2] += bfLo(u.y); a[3] += bfHi(u.y);
        a[4] += bfLo(u.z); a[5] += bfHi(u.z);
        a[6] += bfLo(u.w); a[7] += bfHi(u.w);
      }
    }
  }
#pragma unroll
  for (int k = 0; k < 8; ++k) {
    a[k] += __shfl_xor(a[k], 8);
    a[k] += __shfl_xor(a[k], 16);
    a[k] += __shfl_xor(a[k], 32);
  }
  float nm = norm[wid];
  const float4* bv = (const float4*)bias;     // cols sub*8 .. sub*8+7
  float4 b0 = bv[sub * 2], b1 = bv[sub * 2 + 1];
  if (grp == 0) {
    uint4 o = make_uint4(packbf(a[0] * nm + b0.x, a[1] * nm + b0.y),
                         packbf(a[2] * nm + b0.z, a[3] * nm + b0.w),
                         packbf(a[4] * nm + b1.x, a[5] * nm + b1.y),
                         packbf(a[6] * nm + b1.z, a[7] * nm + b1.w));
    ((uint4*)H)[(size_t)wid * 8 + sub] = o;
  }
}

// ---------------- edge scoring: 8 lanes per query, uint4 row loads ----------------
__global__ __launch_bounds__(256) void k_score(const unsigned short* __restrict__ H,
                                               const int* __restrict__ qs,
                                               const int* __restrict__ qd,
                                               float* __restrict__ out, int q) {
  int t = blockIdx.x * 256 + threadIdx.x;
  int sub = t & 7;
  int q0 = t >> 3;
  float p = 0.f;
  if (q0 < q) {
    int s = qs[q0], d = qd[q0];
    const uint4* Hv = (const uint4*)H;   // row stride 8 uint4
    uint4 a = Hv[(size_t)s * 8 + sub];
    uint4 b = Hv[(size_t)d * 8 + sub];
    p = bfLo(a.x) * bfLo(b.x) + bfHi(a.x) * bfHi(b.x) +
        bfLo(a.y) * bfLo(b.y) + bfHi(a.y) * bfHi(b.y) +
        bfLo(a.z) * bfLo(b.z) + bfHi(a.z) * bfHi(b.z) +
        bfLo(a.w) * bfLo(b.w) + bfHi(a.w) * bfHi(b.w);
  }
  p += __shfl_xor(p, 1);
  p += __shfl_xor(p, 2);
  p += __shfl_xor(p, 4);
  if (sub == 0 && q0 < q) out[q0] = 1.f / (1.f + expf(-p));
}

extern "C" void kernel_launch(void* const* d_in, const int* in_sizes, int n_in,
                              void* d_out, int out_size, void* d_ws, size_t ws_size,
                              hipStream_t stream) {
  const float* feat = (const float*)d_in[0];
  const int* esrc   = (const int*)d_in[1];
  const int* edst   = (const int*)d_in[2];
  const int* qsrc   = (const int*)d_in[3];
  const int* qdst   = (const int*)d_in[4];
  const float* W1   = (const float*)d_in[5];
  const float* b1   = (const float*)d_in[6];
  const float* W2   = (const float*)d_in[7];
  const float* b2   = (const float*)d_in[8];
  float* out = (float*)d_out;

  const int N = in_sizes[0] / 128;
  const int E = in_sizes[1];
  const int Q = in_sizes[3];

  const int G = 256;
  const int NB = (N + 255) >> 8;
  const int chunk = (E + G - 1) / G;
  const int lenS = NB * G;
  const int gScan = lenS / 256;        // blocks per half

  char* w = (char*)d_ws;
  size_t o = 0;
  unsigned short* X1 = (unsigned short*)(w + o); o += align256((size_t)N * 128 * 2);
  unsigned short* X2 = (unsigned short*)(w + o); o += align256((size_t)N * 64 * 2);
  unsigned short* H2 = (unsigned short*)(w + o); o += align256((size_t)N * 64 * 2);
  int* cntIn = (int*)(w + o);       o += align256((size_t)N * 4);
  float* normOut = (float*)(w + o); o += align256((size_t)N * 4);
  float* normIn = (float*)(w + o);  o += align256((size_t)N * 4);
  int* offs = (int*)(w + o);        o += align256((size_t)N * 4);
  int* blk = (int*)(w + o);         o += align256((size_t)lenS * 8);   // D half + S half
  int* sc = (int*)(w + o);          o += align256((size_t)lenS * 8);   // D half + S half
  int* bsums = (int*)(w + o);       o += align256((size_t)8192);
  unsigned short* W1t = (unsigned short*)(w + o); o += align256((size_t)128 * 128 * 2);
  unsigned short* W2t = (unsigned short*)(w + o); o += align256((size_t)64 * 128 * 2);
  unsigned int* pairs = (unsigned int*)(w + o); o += align256((size_t)E * 4);
  unsigned int* keys = (unsigned int*)(w + o); o += align256((size_t)E * 4);
  int* csr = (int*)(w + o);         o += align256((size_t)E * 4);

  int* blkD = blk;        int* blkS = blk + lenS;
  int* scD = sc;          int* scS = sc + lenS;

  // weight prep (bf16 transposed)
  k_prep<<<64, 256, 0, stream>>>(W1, W2, W1t, W2t);

  // graph build (no global atomics); one scan chain covers both halves
  k_coarse_count<<<G, 256, 0, stream>>>(esrc, edst, E, chunk, NB, G, blkD, blkS);
  k_scan1<<<2 * gScan, 256, 0, stream>>>(blk, sc, bsums, 2 * lenS);
  k_scan2<<<2, 512, 0, stream>>>(bsums, gScan);
  k_scan3b<<<2 * gScan, 256, 0, stream>>>(sc, bsums, 2 * lenS);
  k_coarse_scatter<<<G, 256, 0, stream>>>(esrc, edst, E, chunk, NB, G, scD, scS, pairs, keys);
  k_fine<<<2 * NB, 256, 0, stream>>>(pairs, keys, scD, scS, G, E, N, NB,
                                     cntIn, normIn, offs, csr, normOut);

  const int gRows = (N + 63) / 64;
  // layer 1: X1 = (feat*normOut)@W1 ; H1 = relu(agg(X1)*normIn + b1)    [bf16]
  k_mgemm<128, float><<<gRows, 256, 0, stream>>>(feat, normOut, W1t, X1, N);
  k_agg128_relu<<<(N + 3) / 4, 256, 0, stream>>>(X1, csr, offs, cntIn, normIn, b1, X2, N);
  // layer 2: X2b = (H1*normOut)@W2 ; H2 = agg(X2b)*normIn + b2          [bf16]
  k_mgemm<64, unsigned short><<<gRows, 256, 0, stream>>>(X2, normOut, W2t, X1, N);
  k_agg64<<<(N + 3) / 4, 256, 0, stream>>>(X1, csr, offs, cntIn, normIn, b2, H2, N);
  // scoring
  k_score<<<((Q * 8) + 255) / 256, 256, 0, stream>>>(H2, qsrc, qdst, out, Q);
}